// Round 13
// baseline (107.761 us; speedup 1.0000x reference)
//
#include <hip/hip_runtime.h>

// Problem constants (fixed by setup_inputs)
#define T_STEPS 1000
#define BSZ     512
#define CDIM    64
#define CHUNK   32     // steps per phase == bits per output word
#define NCHUNK  32     // chunks 0..31; chunk 31 has 8 live steps
#define TAILN   8
#define REPEAT  2      // PROBE: run the pipeline twice (identical output) so
                       // the recurrence dispatch outlasts the harness's d_ws
                       // poison fills and becomes visible in rocprof top-5.

// Kernel A: s[row] = sum over C of xs[row, :]   (row = t*B + b)
__global__ __launch_bounds__(256) void rowsum_kernel(const float* __restrict__ xs,
                                                     float* __restrict__ s) {
    int g   = blockIdx.x * 256 + threadIdx.x;
    int row = g >> 4;
    int sub = g & 15;
    float4 v = reinterpret_cast<const float4*>(xs)[row * 16 + sub];
    float t = (v.x + v.y) + (v.z + v.w);
    t += __shfl_xor(t, 1);
    t += __shfl_xor(t, 2);
    t += __shfl_xor(t, 4);
    t += __shfl_xor(t, 8);
    if (sub == 0) s[row] = t;
}

// Quarter-folded Izhikevich step (byte-identical arithmetic to R6-R12):
//   vp = 0.01*v^2 + 2.25*v + (iq - 0.25*u),   iq = 0.25*i + 35
//   up = u + 0.005*(0.2*v - u);  reset: v->-65, u->u_old+6 on vp>30

#define PSTEP(SV, KK)                                                      \
    {                                                                      \
        const float iq = fmaf((SV), Sq, cq);                               \
        float a  = fmaf(-0.25f, u, iq);                                    \
        float vp = fmaf(0.01f, v * v, fmaf(2.25f, v, a));                  \
        float up = fmaf(0.005f, fmaf(0.2f, v, -u), u);                     \
        bool z = vp > 30.0f;                                               \
        v = z ? -65.0f : vp;                                               \
        u = z ? u + 6.0f : up;                                             \
        dst[(KK) * 64] = z ? Gq : 0.0f;                                    \
    }

#define CSTEP(R0, R1, KK)                                                  \
    {                                                                      \
        const float g2q = ((R0) + (R1)) + c3q;                             \
        float a2  = fmaf(-0.25f, u2, g2q);                                 \
        float vp2 = fmaf(0.01f, v2 * v2, fmaf(2.25f, v2, a2));             \
        float up2 = fmaf(0.005f, fmaf(0.2f, v2, -u2), u2);                 \
        bool z2 = vp2 > 30.0f;                                             \
        v2 = z2 ? -65.0f : vp2;                                            \
        u2 = z2 ? u2 + 6.0f : up2;                                         \
        acc |= z2 ? (1u << (KK)) : 0u;                                     \
    }

// Kernel B: R8 structure verbatim, wrapped in a REPEAT loop (probe).
// 8 blocks x 192 threads (3 waves). wave0/1 producers, wave2 consumer.
__global__ __launch_bounds__(192, 1) void recurrence_kernel(
    const float* __restrict__ b1, const float* __restrict__ W2,
    const float* __restrict__ b2, const float* __restrict__ Wg2,
    const float* __restrict__ bg2, const float* __restrict__ W3,
    const float* __restrict__ b3, const float* __restrict__ s,
    unsigned* __restrict__ bits) {

    __shared__ float gbuf[2][2][CHUNK][64];   // 32 KB

    const int wave = threadIdx.x >> 6;
    const int lane = threadIdx.x & 63;
    const int b = blockIdx.x * 64 + lane;

    // Fold tiny linear layers into scalars (one-time).
    float S20 = 0.f, S21 = 0.f, d0 = 0.f, d1 = 0.f;
#pragma unroll
    for (int j = 0; j < CDIM; ++j) {
        float w0 = W2[j], w1 = W2[CDIM + j], bj = b1[j];
        S20 += w0; S21 += w1;
        d0 += w0 * bj; d1 += w1 * bj;
    }
    const float S20q = 0.25f * S20;
    const float S21q = 0.25f * S21;
    const float c20q = 0.25f * (d0 + b2[0]) + 35.0f;
    const float c21q = 0.25f * (d1 + b2[1]) + 35.0f;
    const float w30 = W3[0], w31 = W3[1];
    const float G0q = 0.25f * (Wg2[0] * w30 + Wg2[2] * w31);
    const float G1q = 0.25f * (Wg2[1] * w30 + Wg2[3] * w31);
    const float c3q = 0.25f * (bg2[0] * w30 + bg2[1] * w31 + b3[0]) + 35.0f;

    for (int rep = 0; rep < REPEAT; ++rep) {
        if (wave < 2) {
            // -------- producer: neuron `wave` over 1000 steps --------
            const float Sq = wave ? S21q : S20q;
            const float cq = wave ? c21q : c20q;
            const float Gq = wave ? G1q : G0q;
            const int stream = wave;

            float v = -70.f, u = -14.f;
            const float* sp = s + b;

#define LOADP(C, R)                                                        \
            {                                                              \
                const int base = (C) * CHUNK;                              \
                _Pragma("unroll")                                          \
                for (int k = 0; k < CHUNK; ++k) {                          \
                    int t = base + k;                                      \
                    t = t > T_STEPS - 1 ? T_STEPS - 1 : t;                 \
                    R[k] = sp[t * BSZ];                                    \
                }                                                          \
            }

#define PPHASE(C, R, NSTEP)                                                \
            {                                                              \
                float* dst = &gbuf[(C) & 1][stream][0][lane];              \
                _Pragma("unroll")                                          \
                for (int k = 0; k < (NSTEP); ++k) PSTEP(R[k], k)           \
            }

            float R0[CHUNK], R1[CHUNK], R2[CHUNK];
            LOADP(0, R0)
            LOADP(1, R1)

            for (int j = 0; j < 10; ++j) {
                const int c0 = 3 * j;
                // loads FIRST: compute covers latency before pre-barrier drain
                LOADP(c0 + 2, R2)
                PPHASE(c0, R0, CHUNK)
                __syncthreads();
                LOADP(c0 + 3, R0)
                PPHASE(c0 + 1, R1, CHUNK)
                __syncthreads();
                LOADP(c0 + 4, R1)
                PPHASE(c0 + 2, R2, CHUNK)
                __syncthreads();
            }
            // phases 30, 31 (no more loads)
            PPHASE(30, R0, CHUNK)
            __syncthreads();
            PPHASE(31, R1, TAILN)
            __syncthreads();
            __syncthreads();   // consumer drains chunk 31
#undef LOADP
#undef PPHASE
        } else {
            // -------- consumer: neuron 2 over 1000 steps --------
            float v2 = -70.f, u2 = -14.f;
            unsigned accPrev = 0;
            __syncthreads();   // end of phase 0 (chunk 0 now in LDS)
            for (int p = 1; p <= NCHUNK; ++p) {
                const int c = p - 1;
                // store LAST phase's bits first: compute covers the ack
                if (p > 1) bits[(c - 1) * BSZ + b] = accPrev;
                const float* src = &gbuf[c & 1][0][0][lane];
                unsigned acc = 0;
                if (c < NCHUNK - 1) {
                    float r0[CHUNK], r1[CHUNK];
#pragma unroll
                    for (int k = 0; k < CHUNK; ++k) r0[k] = src[k * 64];
#pragma unroll
                    for (int k = 0; k < CHUNK; ++k) r1[k] = src[CHUNK * 64 + k * 64];
#pragma unroll
                    for (int k = 0; k < CHUNK; ++k) CSTEP(r0[k], r1[k], k)
                } else {
                    float r0[TAILN], r1[TAILN];
#pragma unroll
                    for (int k = 0; k < TAILN; ++k) r0[k] = src[k * 64];
#pragma unroll
                    for (int k = 0; k < TAILN; ++k) r1[k] = src[CHUNK * 64 + k * 64];
#pragma unroll
                    for (int k = 0; k < TAILN; ++k) CSTEP(r0[k], r1[k], k)
                }
                accPrev = acc;
                __syncthreads();
            }
            bits[(NCHUNK - 1) * BSZ + b] = accPrev;
        }
    }
}

// Kernel C: expand the 64 KB spike bitmap to 2 MB of floats at full-GPU BW.
__global__ __launch_bounds__(256) void expand_kernel(const unsigned* __restrict__ bits,
                                                     float* __restrict__ out) {
    int g = blockIdx.x * 256 + threadIdx.x;   // g = t*512 + b
    int t = g >> 9;
    int b = g & 511;
    unsigned w = bits[(t >> 5) * BSZ + b];
    out[g] = (float)((w >> (t & 31)) & 1u);
}

extern "C" void kernel_launch(void* const* d_in, const int* in_sizes, int n_in,
                              void* d_out, int out_size, void* d_ws, size_t ws_size,
                              hipStream_t stream) {
    const float* xs  = (const float*)d_in[0];
    const float* b1  = (const float*)d_in[2];
    const float* W2  = (const float*)d_in[3];
    const float* b2  = (const float*)d_in[4];
    const float* Wg2 = (const float*)d_in[5];
    const float* bg2 = (const float*)d_in[6];
    const float* W3  = (const float*)d_in[7];
    const float* b3  = (const float*)d_in[8];
    float* out = (float*)d_out;
    unsigned* bits = (unsigned*)d_ws;          // 32 * 512 * 4 B = 64 KB

    const int rows = T_STEPS * BSZ;                 // 512000
    const int blocksA = rows * 16 / 256;            // 32000
    rowsum_kernel<<<blocksA, 256, 0, stream>>>(xs, out);
    recurrence_kernel<<<8, 192, 0, stream>>>(b1, W2, b2, Wg2, bg2, W3, b3, out, bits);
    expand_kernel<<<rows / 256, 256, 0, stream>>>(bits, out);
}

// Round 14
// 88.946 us; speedup vs baseline: 1.2115x; 1.2115x over previous
//
#include <hip/hip_runtime.h>

// Problem constants (fixed by setup_inputs)
#define T_STEPS 1000
#define BSZ     512
#define CDIM    64
#define CHUNK   32     // steps per phase == bits per output word
#define NCHUNK  32     // chunks 0..31; chunk 31 has 8 live steps
#define TAILN   8
#define NBLK    4      // 4 blocks x 192 threads; each lane owns 2 chains

// Kernel A: s[row] = sum over C of xs[row, :]   (row = t*B + b)
__global__ __launch_bounds__(256) void rowsum_kernel(const float* __restrict__ xs,
                                                     float* __restrict__ s) {
    int g   = blockIdx.x * 256 + threadIdx.x;
    int row = g >> 4;
    int sub = g & 15;
    float4 v = reinterpret_cast<const float4*>(xs)[row * 16 + sub];
    float t = (v.x + v.y) + (v.z + v.w);
    t += __shfl_xor(t, 1);
    t += __shfl_xor(t, 2);
    t += __shfl_xor(t, 4);
    t += __shfl_xor(t, 8);
    if (sub == 0) s[row] = t;
}

// Quarter-folded Izhikevich step (byte-identical arithmetic to R6-R13):
//   vp = 0.01*v^2 + 2.25*v + (iq - 0.25*u),   iq = 0.25*i + 35
//   up = u + 0.005*(0.2*v - u);  reset: v->-65, u->u_old+6 on vp>30

// Producer step for ONE chain (v,u,dst bound by caller).
#define PSTEP1(SV, KK, V, U, DST)                                          \
    {                                                                      \
        const float iq = fmaf((SV), Sq, cq);                               \
        float a  = fmaf(-0.25f, U, iq);                                    \
        float vp = fmaf(0.01f, V * V, fmaf(2.25f, V, a));                  \
        float up = fmaf(0.005f, fmaf(0.2f, V, -U), U);                     \
        bool z = vp > 30.0f;                                               \
        V = z ? -65.0f : vp;                                               \
        U = z ? U + 6.0f : up;                                             \
        DST[(KK) * 64] = z ? Gq : 0.0f;                                    \
    }

// Consumer step for ONE chain.
#define CSTEP1(R0, R1, KK, V2, U2, ACC)                                    \
    {                                                                      \
        const float g2q = ((R0) + (R1)) + c3q;                             \
        float a2  = fmaf(-0.25f, U2, g2q);                                 \
        float vp2 = fmaf(0.01f, V2 * V2, fmaf(2.25f, V2, a2));             \
        float up2 = fmaf(0.005f, fmaf(0.2f, V2, -U2), U2);                 \
        bool z2 = vp2 > 30.0f;                                             \
        V2 = z2 ? -65.0f : vp2;                                            \
        U2 = z2 ? U2 + 6.0f : up2;                                         \
        ACC |= z2 ? (1u << (KK)) : 0u;                                     \
    }

// Kernel B: 4 blocks x 192 threads (3 waves on 3 SIMDs per CU).
// wave0/wave1 -> producer neuron chains, wave2 -> consumer chain.
// Each lane interleaves TWO independent batch elements (b, b+256): the
// second chain's instructions fill the first chain's ~25-cyc dependency
// gaps (R13 probe: waves were ~75% latency-stalled at 1 chain/lane).
__global__ __launch_bounds__(192, 1) void recurrence_kernel(
    const float* __restrict__ b1, const float* __restrict__ W2,
    const float* __restrict__ b2, const float* __restrict__ Wg2,
    const float* __restrict__ bg2, const float* __restrict__ W3,
    const float* __restrict__ b3, const float* __restrict__ s,
    unsigned* __restrict__ bits) {

    // gbuf[buf][stream(neuron)][half(chain)][k][lane] -> conflict-free reads
    __shared__ float gbuf[2][2][2][CHUNK][64];   // 64 KB

    const int wave = threadIdx.x >> 6;
    const int lane = threadIdx.x & 63;
    const int bA = blockIdx.x * 64 + lane;   // chains 0..255
    const int bB = bA + 256;                 // chains 256..511

    // Fold tiny linear layers into scalars (one-time).
    float S20 = 0.f, S21 = 0.f, d0 = 0.f, d1 = 0.f;
#pragma unroll
    for (int j = 0; j < CDIM; ++j) {
        float w0 = W2[j], w1 = W2[CDIM + j], bj = b1[j];
        S20 += w0; S21 += w1;
        d0 += w0 * bj; d1 += w1 * bj;
    }
    const float S20q = 0.25f * S20;
    const float S21q = 0.25f * S21;
    const float c20q = 0.25f * (d0 + b2[0]) + 35.0f;
    const float c21q = 0.25f * (d1 + b2[1]) + 35.0f;
    const float w30 = W3[0], w31 = W3[1];
    const float G0q = 0.25f * (Wg2[0] * w30 + Wg2[2] * w31);
    const float G1q = 0.25f * (Wg2[1] * w30 + Wg2[3] * w31);
    const float c3q = 0.25f * (bg2[0] * w30 + bg2[1] * w31 + b3[0]) + 35.0f;

    if (wave < 2) {
        // -------- producer: neuron `wave`, two chains per lane --------
        const float Sq = wave ? S21q : S20q;
        const float cq = wave ? c21q : c20q;
        const float Gq = wave ? G1q : G0q;
        const int stream = wave;

        float vA = -70.f, uA = -14.f, vB = -70.f, uB = -14.f;
        const float* spA = s + bA;
        const float* spB = s + bB;

#define LOADP(C, RA, RB)                                                   \
        {                                                                  \
            const int base = (C) * CHUNK;                                  \
            _Pragma("unroll")                                              \
            for (int k = 0; k < CHUNK; ++k) {                              \
                int t = base + k;                                          \
                t = t > T_STEPS - 1 ? T_STEPS - 1 : t;                     \
                RA[k] = spA[t * BSZ];                                      \
                RB[k] = spB[t * BSZ];                                      \
            }                                                              \
        }

#define PPHASE(C, RA, RB, NSTEP)                                           \
        {                                                                  \
            float* dstA = &gbuf[(C) & 1][stream][0][0][lane];              \
            float* dstB = &gbuf[(C) & 1][stream][1][0][lane];              \
            _Pragma("unroll")                                              \
            for (int k = 0; k < (NSTEP); ++k) {                            \
                PSTEP1(RA[k], k, vA, uA, dstA)                             \
                PSTEP1(RB[k], k, vB, uB, dstB)                             \
            }                                                              \
        }

        float RA0[CHUNK], RA1[CHUNK], RA2[CHUNK];
        float RB0[CHUNK], RB1[CHUNK], RB2[CHUNK];
        LOADP(0, RA0, RB0)
        LOADP(1, RA1, RB1)

        for (int j = 0; j < 10; ++j) {
            const int c0 = 3 * j;
            // loads FIRST: compute covers latency before pre-barrier drain
            LOADP(c0 + 2, RA2, RB2)
            PPHASE(c0, RA0, RB0, CHUNK)
            __syncthreads();
            LOADP(c0 + 3, RA0, RB0)
            PPHASE(c0 + 1, RA1, RB1, CHUNK)
            __syncthreads();
            LOADP(c0 + 4, RA1, RB1)
            PPHASE(c0 + 2, RA2, RB2, CHUNK)
            __syncthreads();
        }
        // phases 30, 31 (no more loads)
        PPHASE(30, RA0, RB0, CHUNK)
        __syncthreads();
        PPHASE(31, RA1, RB1, TAILN)
        __syncthreads();
        __syncthreads();   // consumer drains chunk 31
#undef LOADP
#undef PPHASE
    } else {
        // -------- consumer: neuron 2, two chains per lane --------
        float v2a = -70.f, u2a = -14.f, v2b = -70.f, u2b = -14.f;
        unsigned accPrevA = 0, accPrevB = 0;
        __syncthreads();   // end of phase 0 (chunk 0 now in LDS)
        for (int p = 1; p <= NCHUNK; ++p) {
            const int c = p - 1;
            // store LAST phase's bits first: compute below covers the acks
            if (p > 1) {
                bits[(c - 1) * BSZ + bA] = accPrevA;
                bits[(c - 1) * BSZ + bB] = accPrevB;
            }
            const float* s0a = &gbuf[c & 1][0][0][0][lane];
            const float* s1a = &gbuf[c & 1][1][0][0][lane];
            const float* s0b = &gbuf[c & 1][0][1][0][lane];
            const float* s1b = &gbuf[c & 1][1][1][0][lane];
            unsigned accA = 0, accB = 0;
            if (c < NCHUNK - 1) {
                float r0a[CHUNK], r1a[CHUNK], r0b[CHUNK], r1b[CHUNK];
#pragma unroll
                for (int k = 0; k < CHUNK; ++k) { r0a[k] = s0a[k * 64]; r1a[k] = s1a[k * 64]; }
#pragma unroll
                for (int k = 0; k < CHUNK; ++k) { r0b[k] = s0b[k * 64]; r1b[k] = s1b[k * 64]; }
#pragma unroll
                for (int k = 0; k < CHUNK; ++k) {
                    CSTEP1(r0a[k], r1a[k], k, v2a, u2a, accA)
                    CSTEP1(r0b[k], r1b[k], k, v2b, u2b, accB)
                }
            } else {
                float r0a[TAILN], r1a[TAILN], r0b[TAILN], r1b[TAILN];
#pragma unroll
                for (int k = 0; k < TAILN; ++k) { r0a[k] = s0a[k * 64]; r1a[k] = s1a[k * 64]; }
#pragma unroll
                for (int k = 0; k < TAILN; ++k) { r0b[k] = s0b[k * 64]; r1b[k] = s1b[k * 64]; }
#pragma unroll
                for (int k = 0; k < TAILN; ++k) {
                    CSTEP1(r0a[k], r1a[k], k, v2a, u2a, accA)
                    CSTEP1(r0b[k], r1b[k], k, v2b, u2b, accB)
                }
            }
            accPrevA = accA;
            accPrevB = accB;
            __syncthreads();
        }
        bits[(NCHUNK - 1) * BSZ + bA] = accPrevA;
        bits[(NCHUNK - 1) * BSZ + bB] = accPrevB;
    }
}

// Kernel C: expand the 64 KB spike bitmap to 2 MB of floats at full-GPU BW.
__global__ __launch_bounds__(256) void expand_kernel(const unsigned* __restrict__ bits,
                                                     float* __restrict__ out) {
    int g = blockIdx.x * 256 + threadIdx.x;   // g = t*512 + b
    int t = g >> 9;
    int b = g & 511;
    unsigned w = bits[(t >> 5) * BSZ + b];
    out[g] = (float)((w >> (t & 31)) & 1u);
}

extern "C" void kernel_launch(void* const* d_in, const int* in_sizes, int n_in,
                              void* d_out, int out_size, void* d_ws, size_t ws_size,
                              hipStream_t stream) {
    const float* xs  = (const float*)d_in[0];
    const float* b1  = (const float*)d_in[2];
    const float* W2  = (const float*)d_in[3];
    const float* b2  = (const float*)d_in[4];
    const float* Wg2 = (const float*)d_in[5];
    const float* bg2 = (const float*)d_in[6];
    const float* W3  = (const float*)d_in[7];
    const float* b3  = (const float*)d_in[8];
    float* out = (float*)d_out;
    unsigned* bits = (unsigned*)d_ws;          // 32 * 512 * 4 B = 64 KB

    const int rows = T_STEPS * BSZ;                 // 512000
    const int blocksA = rows * 16 / 256;            // 32000
    rowsum_kernel<<<blocksA, 256, 0, stream>>>(xs, out);
    recurrence_kernel<<<NBLK, 192, 0, stream>>>(b1, W2, b2, Wg2, bg2, W3, b3, out, bits);
    expand_kernel<<<rows / 256, 256, 0, stream>>>(bits, out);
}

// Round 15
// 72.060 us; speedup vs baseline: 1.4954x; 1.2343x over previous
//
#include <hip/hip_runtime.h>

// Problem constants (fixed by setup_inputs)
#define T_STEPS 1000
#define BSZ     512
#define CDIM    64
#define CHUNK   32     // steps per phase == bits per output word
#define NCHUNK  32     // chunks 0..31; chunk 31 has 8 live steps
#define TAILN   8

// Kernel A: s[row] = sum over C of xs[row, :]   (row = t*B + b)
__global__ __launch_bounds__(256) void rowsum_kernel(const float* __restrict__ xs,
                                                     float* __restrict__ s) {
    int g   = blockIdx.x * 256 + threadIdx.x;
    int row = g >> 4;
    int sub = g & 15;
    float4 v = reinterpret_cast<const float4*>(xs)[row * 16 + sub];
    float t = (v.x + v.y) + (v.z + v.w);
    t += __shfl_xor(t, 1);
    t += __shfl_xor(t, 2);
    t += __shfl_xor(t, 4);
    t += __shfl_xor(t, 8);
    if (sub == 0) s[row] = t;
}

// Shortened-dependency Izhikevich step (reassociated vs R8; 4 dep levels):
//   vp = v*(0.01v + 2.25) + (iq - 0.25u),  iq = 0.25*i + 35
//   up = 0.995*u + 0.001*v        (exact decimal folds of the norse form)
//   reset: v->-65, u->u_old+6 on vp>30

#define PSTEP(SV, KK)                                                      \
    {                                                                      \
        const float iq   = fmaf((SV), Sq, cq);                             \
        const float a    = fmaf(-0.25f, u, iq);                            \
        const float poly = fmaf(0.01f, v, 2.25f);                          \
        const float vp   = fmaf(v, poly, a);                               \
        const float up   = fmaf(0.995f, u, 0.001f * v);                    \
        const float nu   = u + 6.0f;                                       \
        bool z = vp > 30.0f;                                               \
        v = z ? -65.0f : vp;                                               \
        u = z ? nu : up;                                                   \
        dst[(KK) * 128] = z ? Gq : 0.0f;                                   \
    }

#define CSTEP(R01, KK)                                                     \
    {                                                                      \
        const float g2q  = ((R01).x + (R01).y) + c3q;                      \
        const float a2   = fmaf(-0.25f, u2, g2q);                          \
        const float poly2 = fmaf(0.01f, v2, 2.25f);                        \
        const float vp2  = fmaf(v2, poly2, a2);                            \
        const float up2  = fmaf(0.995f, u2, 0.001f * v2);                  \
        const float nu2  = u2 + 6.0f;                                      \
        bool z2 = vp2 > 30.0f;                                             \
        v2 = z2 ? -65.0f : vp2;                                            \
        u2 = z2 ? nu2 : up2;                                               \
        acc |= z2 ? (1u << (KK)) : 0u;                                     \
    }

// Kernel B: 8 blocks x 192 threads (3 waves on 3 SIMDs per CU) — R8 shape.
// wave0/wave1 -> producer neuron chains, wave2 -> consumer neuron chain.
// LDS layout [k][lane][{n0,n1}] so the consumer reads one float2 per step.
__global__ __launch_bounds__(192, 1) void recurrence_kernel(
    const float* __restrict__ b1, const float* __restrict__ W2,
    const float* __restrict__ b2, const float* __restrict__ Wg2,
    const float* __restrict__ bg2, const float* __restrict__ W3,
    const float* __restrict__ b3, const float* __restrict__ s,
    unsigned* __restrict__ bits) {

    __shared__ float gbuf[2][CHUNK][64][2];   // 32 KB

    const int wave = threadIdx.x >> 6;
    const int lane = threadIdx.x & 63;
    const int b = blockIdx.x * 64 + lane;

    // Fold tiny linear layers into scalars (one-time).
    float S20 = 0.f, S21 = 0.f, d0 = 0.f, d1 = 0.f;
#pragma unroll
    for (int j = 0; j < CDIM; ++j) {
        float w0 = W2[j], w1 = W2[CDIM + j], bj = b1[j];
        S20 += w0; S21 += w1;
        d0 += w0 * bj; d1 += w1 * bj;
    }
    const float S20q = 0.25f * S20;
    const float S21q = 0.25f * S21;
    const float c20q = 0.25f * (d0 + b2[0]) + 35.0f;
    const float c21q = 0.25f * (d1 + b2[1]) + 35.0f;
    const float w30 = W3[0], w31 = W3[1];
    const float G0q = 0.25f * (Wg2[0] * w30 + Wg2[2] * w31);
    const float G1q = 0.25f * (Wg2[1] * w30 + Wg2[3] * w31);
    const float c3q = 0.25f * (bg2[0] * w30 + bg2[1] * w31 + b3[0]) + 35.0f;

    if (wave < 2) {
        // -------- producer: neuron `wave` over 1000 steps --------
        const float Sq = wave ? S21q : S20q;
        const float cq = wave ? c21q : c20q;
        const float Gq = wave ? G1q : G0q;
        const int stream = wave;

        float v = -70.f, u = -14.f;
        const float* sp = s + b;

#define LOADP(C, R)                                                        \
        {                                                                  \
            const int base = (C) * CHUNK;                                  \
            _Pragma("unroll")                                              \
            for (int k = 0; k < CHUNK; ++k) {                              \
                int t = base + k;                                          \
                t = t > T_STEPS - 1 ? T_STEPS - 1 : t;                     \
                R[k] = sp[t * BSZ];                                        \
            }                                                              \
        }

#define PPHASE(C, R, NSTEP)                                                \
        {                                                                  \
            float* dst = &gbuf[(C) & 1][0][lane][stream];                  \
            _Pragma("unroll")                                              \
            for (int k = 0; k < (NSTEP); ++k) PSTEP(R[k], k)               \
        }

        float R0[CHUNK], R1[CHUNK], R2[CHUNK];
        LOADP(0, R0)
        LOADP(1, R1)

        for (int j = 0; j < 10; ++j) {
            const int c0 = 3 * j;
            // loads FIRST: the phase's compute covers load latency before
            // the pre-barrier vmcnt drain
            LOADP(c0 + 2, R2)
            PPHASE(c0, R0, CHUNK)
            __syncthreads();
            LOADP(c0 + 3, R0)
            PPHASE(c0 + 1, R1, CHUNK)
            __syncthreads();
            LOADP(c0 + 4, R1)
            PPHASE(c0 + 2, R2, CHUNK)
            __syncthreads();
        }
        // phases 30, 31 (no more loads)
        PPHASE(30, R0, CHUNK)
        __syncthreads();
        PPHASE(31, R1, TAILN)
        __syncthreads();
        __syncthreads();   // consumer drains chunk 31
#undef LOADP
#undef PPHASE
    } else {
        // -------- consumer: neuron 2 over 1000 steps --------
        float v2 = -70.f, u2 = -14.f;
        unsigned accPrev = 0;
        __syncthreads();   // end of phase 0 (chunk 0 now in LDS)
        for (int p = 1; p <= NCHUNK; ++p) {
            const int c = p - 1;
            // store LAST phase's bits first: compute below covers the ack
            if (p > 1) bits[(c - 1) * BSZ + b] = accPrev;
            const float2* src = reinterpret_cast<const float2*>(&gbuf[c & 1][0][lane][0]);
            unsigned acc = 0;
            if (c < NCHUNK - 1) {
                float2 r[CHUNK];
#pragma unroll
                for (int k = 0; k < CHUNK; ++k) r[k] = src[k * 64];
#pragma unroll
                for (int k = 0; k < CHUNK; ++k) CSTEP(r[k], k)
            } else {
                float2 r[TAILN];
#pragma unroll
                for (int k = 0; k < TAILN; ++k) r[k] = src[k * 64];
#pragma unroll
                for (int k = 0; k < TAILN; ++k) CSTEP(r[k], k)
            }
            accPrev = acc;
            __syncthreads();
        }
        bits[(NCHUNK - 1) * BSZ + b] = accPrev;
    }
}

// Kernel C: expand the 64 KB spike bitmap to 2 MB of floats at full-GPU BW.
__global__ __launch_bounds__(256) void expand_kernel(const unsigned* __restrict__ bits,
                                                     float* __restrict__ out) {
    int g = blockIdx.x * 256 + threadIdx.x;   // g = t*512 + b
    int t = g >> 9;
    int b = g & 511;
    unsigned w = bits[(t >> 5) * BSZ + b];
    out[g] = (float)((w >> (t & 31)) & 1u);
}

extern "C" void kernel_launch(void* const* d_in, const int* in_sizes, int n_in,
                              void* d_out, int out_size, void* d_ws, size_t ws_size,
                              hipStream_t stream) {
    const float* xs  = (const float*)d_in[0];
    const float* b1  = (const float*)d_in[2];
    const float* W2  = (const float*)d_in[3];
    const float* b2  = (const float*)d_in[4];
    const float* Wg2 = (const float*)d_in[5];
    const float* bg2 = (const float*)d_in[6];
    const float* W3  = (const float*)d_in[7];
    const float* b3  = (const float*)d_in[8];
    float* out = (float*)d_out;
    unsigned* bits = (unsigned*)d_ws;          // 32 * 512 * 4 B = 64 KB

    const int rows = T_STEPS * BSZ;                 // 512000
    const int blocksA = rows * 16 / 256;            // 32000
    rowsum_kernel<<<blocksA, 256, 0, stream>>>(xs, out);
    recurrence_kernel<<<8, 192, 0, stream>>>(b1, W2, b2, Wg2, bg2, W3, b3, out, bits);
    expand_kernel<<<rows / 256, 256, 0, stream>>>(bits, out);
}